// Round 1
// baseline (1100.148 us; speedup 1.0000x reference)
//
#include <hip/hip_runtime.h>

constexpr int kNodes = 10000;
constexpr int kEdges = 640000;
constexpr int kD = 128;

// --- Kernel 1: scatter-add  h[dst[e]] += feature[src[e]] ---------------------
// 32 lanes per edge; each lane handles 4 contiguous dims via float4.
__global__ void scatter_add_kernel(const float* __restrict__ feature,
                                   const int* __restrict__ src,
                                   const int* __restrict__ dst,
                                   float* __restrict__ h) {
    long long tid = (long long)blockIdx.x * blockDim.x + threadIdx.x;
    int e    = (int)(tid >> 5);
    int lane = (int)(tid & 31);
    if (e >= kEdges) return;
    int s = src[e];
    int d = dst[e];
    const float4 v = *reinterpret_cast<const float4*>(feature + (size_t)s * kD + lane * 4);
    float* hp = h + (size_t)d * kD + lane * 4;
    atomicAdd(hp + 0, v.x);
    atomicAdd(hp + 1, v.y);
    atomicAdd(hp + 2, v.z);
    atomicAdd(hp + 3, v.w);
}

// --- Kernel 2: out = h @ W + b ----------------------------------------------
// 32 threads per row; each thread computes 4 output columns.
__global__ void gemm_bias_kernel(const float* __restrict__ h,
                                 const float* __restrict__ W,
                                 const float* __restrict__ b,
                                 float* __restrict__ out) {
    int t   = blockIdx.x * blockDim.x + threadIdx.x;
    int row = t >> 5;
    int j0  = (t & 31) * 4;
    if (row >= kNodes) return;

    const float* hrow = h + (size_t)row * kD;
    float4 acc = make_float4(0.f, 0.f, 0.f, 0.f);
#pragma unroll 8
    for (int k = 0; k < kD; ++k) {
        float hv = hrow[k];                       // broadcast within 32-lane group
        float4 w4 = *reinterpret_cast<const float4*>(W + (size_t)k * kD + j0);
        acc.x += hv * w4.x;
        acc.y += hv * w4.y;
        acc.z += hv * w4.z;
        acc.w += hv * w4.w;
    }
    const float4 bb = *reinterpret_cast<const float4*>(b + j0);
    acc.x += bb.x; acc.y += bb.y; acc.z += bb.z; acc.w += bb.w;
    *reinterpret_cast<float4*>(out + (size_t)row * kD + j0) = acc;
}

extern "C" void kernel_launch(void* const* d_in, const int* in_sizes, int n_in,
                              void* d_out, int out_size, void* d_ws, size_t ws_size,
                              hipStream_t stream) {
    const float* feature = (const float*)d_in[0];
    const int*   src     = (const int*)d_in[1];
    const int*   dst     = (const int*)d_in[2];
    const float* W       = (const float*)d_in[3];
    const float* b       = (const float*)d_in[4];
    float*       out     = (float*)d_out;
    float*       h       = (float*)d_ws;   // [kNodes][kD] f32 accumulator

    // zero the accumulator (workspace is poisoned 0xAA once, never re-poisoned)
    hipMemsetAsync(h, 0, (size_t)kNodes * kD * sizeof(float), stream);

    {   // scatter-add: 32 threads per edge
        long long total = (long long)kEdges * 32;
        int threads = 256;
        int blocks  = (int)((total + threads - 1) / threads);
        scatter_add_kernel<<<blocks, threads, 0, stream>>>(feature, src, dst, h);
    }
    {   // GEMM + bias: 32 threads per row
        int total   = kNodes * 32;
        int threads = 256;
        int blocks  = (total + threads - 1) / threads;
        gemm_bias_kernel<<<blocks, threads, 0, stream>>>(h, W, b, out);
    }
}

// Round 2
// 196.426 us; speedup vs baseline: 5.6008x; 5.6008x over previous
//
#include <hip/hip_runtime.h>

constexpr int kNodes = 10000;
constexpr int kEdges = 640000;
constexpr int kD = 128;

// ---------------------------------------------------------------------------
// Path A (fallback): direct atomic scatter-add (round-1 kernel)
// ---------------------------------------------------------------------------
__global__ void scatter_add_kernel(const float* __restrict__ feature,
                                   const int* __restrict__ src,
                                   const int* __restrict__ dst,
                                   float* __restrict__ h) {
    long long tid = (long long)blockIdx.x * blockDim.x + threadIdx.x;
    int e    = (int)(tid >> 5);
    int lane = (int)(tid & 31);
    if (e >= kEdges) return;
    int s = src[e];
    int d = dst[e];
    const float4 v = *reinterpret_cast<const float4*>(feature + (size_t)s * kD + lane * 4);
    float* hp = h + (size_t)d * kD + lane * 4;
    atomicAdd(hp + 0, v.x);
    atomicAdd(hp + 1, v.y);
    atomicAdd(hp + 2, v.z);
    atomicAdd(hp + 3, v.w);
}

// ---------------------------------------------------------------------------
// Path B: CSR build + register-accumulated gather (no float atomics)
// ---------------------------------------------------------------------------
__global__ void histogram_kernel(const int* __restrict__ dst,
                                 int* __restrict__ counts) {
    int e = blockIdx.x * blockDim.x + threadIdx.x;
    if (e >= kEdges) return;
    atomicAdd(&counts[dst[e]], 1);
}

// Single-block exclusive scan over kNodes counts -> offsets[kNodes+1], cursor copy.
__global__ void scan_kernel(const int* __restrict__ counts,
                            int* __restrict__ offsets,
                            int* __restrict__ cursor) {
    __shared__ int lds[256];
    __shared__ int running;
    int t = threadIdx.x;
    if (t == 0) running = 0;
    __syncthreads();
    for (int base = 0; base < kNodes; base += 256) {
        int i = base + t;
        int v = (i < kNodes) ? counts[i] : 0;
        lds[t] = v;
        __syncthreads();
        // Hillis-Steele inclusive scan
        for (int off = 1; off < 256; off <<= 1) {
            int add = (t >= off) ? lds[t - off] : 0;
            __syncthreads();
            lds[t] += add;
            __syncthreads();
        }
        int incl = lds[t];
        int excl = incl - v;
        if (i < kNodes) {
            int o = running + excl;
            offsets[i] = o;
            cursor[i]  = o;
        }
        __syncthreads();               // everyone has read `running`
        if (t == 255) running += incl; // lds[255] = block total
        __syncthreads();
    }
    if (t == 0) offsets[kNodes] = running;
}

__global__ void fill_kernel(const int* __restrict__ src,
                            const int* __restrict__ dst,
                            int* __restrict__ cursor,
                            int* __restrict__ csr_src) {
    int e = blockIdx.x * blockDim.x + threadIdx.x;
    if (e >= kEdges) return;
    int d   = dst[e];
    int pos = atomicAdd(&cursor[d], 1);
    csr_src[pos] = src[e];
}

// One 64-lane wave per node; each lane owns 2 contiguous dims (float2).
__global__ void gather_kernel(const float* __restrict__ feature,
                              const int* __restrict__ offsets,
                              const int* __restrict__ csr_src,
                              float* __restrict__ h) {
    int node = blockIdx.x * (blockDim.x >> 6) + (threadIdx.x >> 6);
    int lane = threadIdx.x & 63;
    if (node >= kNodes) return;
    int beg = offsets[node];
    int end = offsets[node + 1];
    float2 acc = make_float2(0.f, 0.f);
    int i = beg;
    // 4-deep unroll: 4 independent feature loads in flight
    for (; i + 4 <= end; i += 4) {
        int s0 = csr_src[i + 0];
        int s1 = csr_src[i + 1];
        int s2 = csr_src[i + 2];
        int s3 = csr_src[i + 3];
        float2 v0 = *reinterpret_cast<const float2*>(feature + (size_t)s0 * kD + lane * 2);
        float2 v1 = *reinterpret_cast<const float2*>(feature + (size_t)s1 * kD + lane * 2);
        float2 v2 = *reinterpret_cast<const float2*>(feature + (size_t)s2 * kD + lane * 2);
        float2 v3 = *reinterpret_cast<const float2*>(feature + (size_t)s3 * kD + lane * 2);
        acc.x += v0.x + v1.x + v2.x + v3.x;
        acc.y += v0.y + v1.y + v2.y + v3.y;
    }
    for (; i < end; ++i) {
        int s = csr_src[i];
        float2 v = *reinterpret_cast<const float2*>(feature + (size_t)s * kD + lane * 2);
        acc.x += v.x;
        acc.y += v.y;
    }
    *reinterpret_cast<float2*>(h + (size_t)node * kD + lane * 2) = acc;
}

// --- out = h @ W + b --------------------------------------------------------
__global__ void gemm_bias_kernel(const float* __restrict__ h,
                                 const float* __restrict__ W,
                                 const float* __restrict__ b,
                                 float* __restrict__ out) {
    int t   = blockIdx.x * blockDim.x + threadIdx.x;
    int row = t >> 5;
    int j0  = (t & 31) * 4;
    if (row >= kNodes) return;

    const float* hrow = h + (size_t)row * kD;
    float4 acc = make_float4(0.f, 0.f, 0.f, 0.f);
#pragma unroll 8
    for (int k = 0; k < kD; ++k) {
        float hv = hrow[k];
        float4 w4 = *reinterpret_cast<const float4*>(W + (size_t)k * kD + j0);
        acc.x += hv * w4.x;
        acc.y += hv * w4.y;
        acc.z += hv * w4.z;
        acc.w += hv * w4.w;
    }
    const float4 bb = *reinterpret_cast<const float4*>(b + j0);
    acc.x += bb.x; acc.y += bb.y; acc.z += bb.z; acc.w += bb.w;
    *reinterpret_cast<float4*>(out + (size_t)row * kD + j0) = acc;
}

extern "C" void kernel_launch(void* const* d_in, const int* in_sizes, int n_in,
                              void* d_out, int out_size, void* d_ws, size_t ws_size,
                              hipStream_t stream) {
    const float* feature = (const float*)d_in[0];
    const int*   src     = (const int*)d_in[1];
    const int*   dst     = (const int*)d_in[2];
    const float* W       = (const float*)d_in[3];
    const float* b       = (const float*)d_in[4];
    float*       out     = (float*)d_out;

    // Workspace layout
    //   h        : kNodes*kD floats            (5,120,000 B)
    //   counts   : kNodes ints                 (40,000 B)
    //   offsets  : kNodes+1 ints               (40,004 B)
    //   cursor   : kNodes ints                 (40,000 B)
    //   csr_src  : kEdges ints                 (2,560,000 B)
    char* ws = (char*)d_ws;
    size_t off = 0;
    float* h = (float*)(ws + off);       off += (size_t)kNodes * kD * sizeof(float);
    int* counts  = (int*)(ws + off);     off += (size_t)kNodes * sizeof(int);
    int* offsets = (int*)(ws + off);     off += (size_t)(kNodes + 1) * sizeof(int);
    int* cursor  = (int*)(ws + off);     off += (size_t)kNodes * sizeof(int);
    int* csr_src = (int*)(ws + off);     off += (size_t)kEdges * sizeof(int);
    const size_t needed = off;

    if (ws_size >= needed) {
        // --- Path B: CSR build + gather (no float atomics) ---
        hipMemsetAsync(counts, 0, (size_t)kNodes * sizeof(int), stream);

        int threads = 256;
        int eblocks = (kEdges + threads - 1) / threads;
        histogram_kernel<<<eblocks, threads, 0, stream>>>(dst, counts);
        scan_kernel<<<1, 256, 0, stream>>>(counts, offsets, cursor);
        fill_kernel<<<eblocks, threads, 0, stream>>>(src, dst, cursor, csr_src);

        int waves_per_block = threads / 64;
        int gblocks = (kNodes + waves_per_block - 1) / waves_per_block;
        gather_kernel<<<gblocks, threads, 0, stream>>>(feature, offsets, csr_src, h);
    } else {
        // --- Path A fallback: atomic scatter ---
        hipMemsetAsync(h, 0, (size_t)kNodes * kD * sizeof(float), stream);
        long long total = (long long)kEdges * 32;
        int threads = 256;
        int blocks  = (int)((total + threads - 1) / threads);
        scatter_add_kernel<<<blocks, threads, 0, stream>>>(feature, src, dst, h);
    }

    {   // GEMM + bias: 32 threads per row
        int total   = kNodes * 32;
        int threads = 256;
        int blocks  = (total + threads - 1) / threads;
        gemm_bias_kernel<<<blocks, threads, 0, stream>>>(h, W, b, out);
    }
}

// Round 3
// 146.949 us; speedup vs baseline: 7.4866x; 1.3367x over previous
//
#include <hip/hip_runtime.h>

constexpr int kNodes = 10000;
constexpr int kEdges = 640000;
constexpr int kD = 128;

// ---------------------------------------------------------------------------
// Path A (fallback): direct atomic scatter-add
// ---------------------------------------------------------------------------
__global__ void scatter_add_kernel(const float* __restrict__ feature,
                                   const int* __restrict__ src,
                                   const int* __restrict__ dst,
                                   float* __restrict__ h) {
    long long tid = (long long)blockIdx.x * blockDim.x + threadIdx.x;
    int e    = (int)(tid >> 5);
    int lane = (int)(tid & 31);
    if (e >= kEdges) return;
    int s = src[e];
    int d = dst[e];
    const float4 v = *reinterpret_cast<const float4*>(feature + (size_t)s * kD + lane * 4);
    float* hp = h + (size_t)d * kD + lane * 4;
    atomicAdd(hp + 0, v.x);
    atomicAdd(hp + 1, v.y);
    atomicAdd(hp + 2, v.z);
    atomicAdd(hp + 3, v.w);
}

// ---------------------------------------------------------------------------
// Path B: CSR build + register-accumulated gather (no float atomics)
// ---------------------------------------------------------------------------
__global__ void histogram_kernel(const int* __restrict__ dst,
                                 int* __restrict__ counts) {
    int e = blockIdx.x * blockDim.x + threadIdx.x;
    if (e >= kEdges) return;
    atomicAdd(&counts[dst[e]], 1);
}

// Parallel single-kernel scan: 1024 threads, 10 elements/thread in registers,
// one 1024-wide Hillis-Steele over thread sums.
constexpr int kScanThreads = 1024;
constexpr int kPerThread   = 10;   // 1024*10 = 10240 >= kNodes

__global__ __launch_bounds__(kScanThreads)
void scan_kernel(const int* __restrict__ counts,
                 int* __restrict__ offsets,
                 int* __restrict__ cursor) {
    __shared__ int lds[kScanThreads];
    int t = threadIdx.x;
    int base = t * kPerThread;

    int v[kPerThread];
    int sum = 0;
#pragma unroll
    for (int i = 0; i < kPerThread; ++i) {
        int idx = base + i;
        v[i] = (idx < kNodes) ? counts[idx] : 0;
        sum += v[i];
    }

    lds[t] = sum;
    __syncthreads();
#pragma unroll
    for (int off = 1; off < kScanThreads; off <<= 1) {
        int add = (t >= off) ? lds[t - off] : 0;
        __syncthreads();
        lds[t] += add;
        __syncthreads();
    }
    int excl = lds[t] - sum;

    int run = excl;
#pragma unroll
    for (int i = 0; i < kPerThread; ++i) {
        int idx = base + i;
        if (idx < kNodes) {
            offsets[idx] = run;
            cursor[idx]  = run;
        }
        run += v[i];
    }
    if (t == 0) offsets[kNodes] = lds[kScanThreads - 1];
}

__global__ void fill_kernel(const int* __restrict__ src,
                            const int* __restrict__ dst,
                            int* __restrict__ cursor,
                            int* __restrict__ csr_src) {
    int e = blockIdx.x * blockDim.x + threadIdx.x;
    if (e >= kEdges) return;
    int d   = dst[e];
    int pos = atomicAdd(&cursor[d], 1);
    csr_src[pos] = src[e];
}

// One 64-lane wave per node; each lane owns 2 contiguous dims (float2).
__global__ void gather_kernel(const float* __restrict__ feature,
                              const int* __restrict__ offsets,
                              const int* __restrict__ csr_src,
                              float* __restrict__ h) {
    int node = blockIdx.x * (blockDim.x >> 6) + (threadIdx.x >> 6);
    int lane = threadIdx.x & 63;
    if (node >= kNodes) return;
    int beg = offsets[node];
    int end = offsets[node + 1];
    float2 acc = make_float2(0.f, 0.f);
    int i = beg;
    // 8-deep unroll: 8 independent feature loads in flight
    for (; i + 8 <= end; i += 8) {
        float2 vv[8];
#pragma unroll
        for (int u = 0; u < 8; ++u) {
            int s = csr_src[i + u];
            vv[u] = *reinterpret_cast<const float2*>(feature + (size_t)s * kD + lane * 2);
        }
#pragma unroll
        for (int u = 0; u < 8; ++u) {
            acc.x += vv[u].x;
            acc.y += vv[u].y;
        }
    }
    for (; i < end; ++i) {
        int s = csr_src[i];
        float2 v = *reinterpret_cast<const float2*>(feature + (size_t)s * kD + lane * 2);
        acc.x += v.x;
        acc.y += v.y;
    }
    *reinterpret_cast<float2*>(h + (size_t)node * kD + lane * 2) = acc;
}

// --- out = h @ W + b, W staged in LDS ---------------------------------------
// 256 threads = 8 rows x 32 col-groups; 1250 blocks.
__global__ __launch_bounds__(256)
void gemm_bias_kernel(const float* __restrict__ h,
                      const float* __restrict__ W,
                      const float* __restrict__ b,
                      float* __restrict__ out) {
    __shared__ float Wl[kD * kD];   // 64 KB
    int t = threadIdx.x;

    // cooperative W load: 4096 float4s across 256 threads
#pragma unroll
    for (int i = 0; i < 16; ++i) {
        int idx = t + i * 256;
        reinterpret_cast<float4*>(Wl)[idx] =
            reinterpret_cast<const float4*>(W)[idx];
    }
    __syncthreads();

    int row = blockIdx.x * 8 + (t >> 5);
    int j0  = (t & 31) * 4;
    if (row >= kNodes) return;

    const float* hrow = h + (size_t)row * kD;
    float4 acc = make_float4(0.f, 0.f, 0.f, 0.f);
#pragma unroll 4
    for (int k = 0; k < kD; k += 4) {
        float4 hv4 = *reinterpret_cast<const float4*>(hrow + k);  // broadcast in 32-group
        const float* wk = Wl + (size_t)k * kD + j0;
        float4 w0 = *reinterpret_cast<const float4*>(wk + 0 * kD);
        float4 w1 = *reinterpret_cast<const float4*>(wk + 1 * kD);
        float4 w2 = *reinterpret_cast<const float4*>(wk + 2 * kD);
        float4 w3 = *reinterpret_cast<const float4*>(wk + 3 * kD);
        acc.x += hv4.x * w0.x + hv4.y * w1.x + hv4.z * w2.x + hv4.w * w3.x;
        acc.y += hv4.x * w0.y + hv4.y * w1.y + hv4.z * w2.y + hv4.w * w3.y;
        acc.z += hv4.x * w0.z + hv4.y * w1.z + hv4.z * w2.z + hv4.w * w3.z;
        acc.w += hv4.x * w0.w + hv4.y * w1.w + hv4.z * w2.w + hv4.w * w3.w;
    }
    const float4 bb = *reinterpret_cast<const float4*>(b + j0);
    acc.x += bb.x; acc.y += bb.y; acc.z += bb.z; acc.w += bb.w;
    *reinterpret_cast<float4*>(out + (size_t)row * kD + j0) = acc;
}

extern "C" void kernel_launch(void* const* d_in, const int* in_sizes, int n_in,
                              void* d_out, int out_size, void* d_ws, size_t ws_size,
                              hipStream_t stream) {
    const float* feature = (const float*)d_in[0];
    const int*   src     = (const int*)d_in[1];
    const int*   dst     = (const int*)d_in[2];
    const float* W       = (const float*)d_in[3];
    const float* b       = (const float*)d_in[4];
    float*       out     = (float*)d_out;

    // Workspace layout
    char* ws = (char*)d_ws;
    size_t off = 0;
    float* h = (float*)(ws + off);       off += (size_t)kNodes * kD * sizeof(float);
    int* counts  = (int*)(ws + off);     off += (size_t)kNodes * sizeof(int);
    int* offsets = (int*)(ws + off);     off += (size_t)(kNodes + 1) * sizeof(int);
    int* cursor  = (int*)(ws + off);     off += (size_t)kNodes * sizeof(int);
    int* csr_src = (int*)(ws + off);     off += (size_t)kEdges * sizeof(int);
    const size_t needed = off;

    if (ws_size >= needed) {
        hipMemsetAsync(counts, 0, (size_t)kNodes * sizeof(int), stream);

        int threads = 256;
        int eblocks = (kEdges + threads - 1) / threads;
        histogram_kernel<<<eblocks, threads, 0, stream>>>(dst, counts);
        scan_kernel<<<1, kScanThreads, 0, stream>>>(counts, offsets, cursor);
        fill_kernel<<<eblocks, threads, 0, stream>>>(src, dst, cursor, csr_src);

        int waves_per_block = threads / 64;
        int gblocks = (kNodes + waves_per_block - 1) / waves_per_block;
        gather_kernel<<<gblocks, threads, 0, stream>>>(feature, offsets, csr_src, h);
    } else {
        hipMemsetAsync(h, 0, (size_t)kNodes * kD * sizeof(float), stream);
        long long total = (long long)kEdges * 32;
        int threads = 256;
        int blocks  = (int)((total + threads - 1) / threads);
        scatter_add_kernel<<<blocks, threads, 0, stream>>>(feature, src, dst, h);
    }

    {   // GEMM + bias: 8 rows per 256-thread block
        int blocks = (kNodes + 7) / 8;
        gemm_bias_kernel<<<blocks, 256, 0, stream>>>(h, W, b, out);
    }
}

// Round 4
// 142.176 us; speedup vs baseline: 7.7379x; 1.0336x over previous
//
#include <hip/hip_runtime.h>

constexpr int kNodes  = 10000;
constexpr int kEdges  = 640000;
constexpr int kD      = 128;
constexpr int kChains = 4;      // interleaved linked lists per node

// ---------------------------------------------------------------------------
// Path A (fallback): direct atomic scatter-add
// ---------------------------------------------------------------------------
__global__ void scatter_add_kernel(const float* __restrict__ feature,
                                   const int* __restrict__ src,
                                   const int* __restrict__ dst,
                                   float* __restrict__ h) {
    long long tid = (long long)blockIdx.x * blockDim.x + threadIdx.x;
    int e    = (int)(tid >> 5);
    int lane = (int)(tid & 31);
    if (e >= kEdges) return;
    int s = src[e];
    int d = dst[e];
    const float4 v = *reinterpret_cast<const float4*>(feature + (size_t)s * kD + lane * 4);
    float* hp = h + (size_t)d * kD + lane * 4;
    atomicAdd(hp + 0, v.x);
    atomicAdd(hp + 1, v.y);
    atomicAdd(hp + 2, v.z);
    atomicAdd(hp + 3, v.w);
}

// ---------------------------------------------------------------------------
// Path B: linked-list bucket build + chase gather (no float atomics,
//         no scattered small writes — packed[] written coalesced at index e)
// ---------------------------------------------------------------------------
__global__ void build_ll_kernel(const int* __restrict__ src,
                                const int* __restrict__ dst,
                                int* __restrict__ head,      // [kNodes*kChains]
                                int2* __restrict__ packed) { // [kEdges] {src, next}
    int e = blockIdx.x * blockDim.x + threadIdx.x;
    if (e >= kEdges) return;
    int s = src[e];
    int d = dst[e];
    int slot = d * kChains + (e & (kChains - 1));
    int old = atomicExch(&head[slot], e);
    packed[e] = make_int2(s, old);
}

// One 64-lane wave per node; 4 chains chased concurrently (independent
// dependent-load chains -> 4x latency overlap). Lane owns 2 dims (float2).
__global__ void gather_ll_kernel(const float* __restrict__ feature,
                                 const int* __restrict__ head,
                                 const int2* __restrict__ packed,
                                 float* __restrict__ h) {
    int node = blockIdx.x * (blockDim.x >> 6) + (threadIdx.x >> 6);
    int lane = threadIdx.x & 63;
    if (node >= kNodes) return;

    int e0 = head[node * kChains + 0];
    int e1 = head[node * kChains + 1];
    int e2 = head[node * kChains + 2];
    int e3 = head[node * kChains + 3];

    float2 acc0 = make_float2(0.f, 0.f);
    float2 acc1 = make_float2(0.f, 0.f);
    float2 acc2 = make_float2(0.f, 0.f);
    float2 acc3 = make_float2(0.f, 0.f);

    while (e0 >= 0 || e1 >= 0 || e2 >= 0 || e3 >= 0) {
        if (e0 >= 0) {
            int2 p = packed[e0];
            float2 v = *reinterpret_cast<const float2*>(feature + (size_t)p.x * kD + lane * 2);
            acc0.x += v.x; acc0.y += v.y;
            e0 = p.y;
        }
        if (e1 >= 0) {
            int2 p = packed[e1];
            float2 v = *reinterpret_cast<const float2*>(feature + (size_t)p.x * kD + lane * 2);
            acc1.x += v.x; acc1.y += v.y;
            e1 = p.y;
        }
        if (e2 >= 0) {
            int2 p = packed[e2];
            float2 v = *reinterpret_cast<const float2*>(feature + (size_t)p.x * kD + lane * 2);
            acc2.x += v.x; acc2.y += v.y;
            e2 = p.y;
        }
        if (e3 >= 0) {
            int2 p = packed[e3];
            float2 v = *reinterpret_cast<const float2*>(feature + (size_t)p.x * kD + lane * 2);
            acc3.x += v.x; acc3.y += v.y;
            e3 = p.y;
        }
    }

    float2 acc = make_float2((acc0.x + acc1.x) + (acc2.x + acc3.x),
                             (acc0.y + acc1.y) + (acc2.y + acc3.y));
    *reinterpret_cast<float2*>(h + (size_t)node * kD + lane * 2) = acc;
}

// --- out = h @ W + b, W staged in LDS, 2 rows/thread ------------------------
// 256 threads = 8 row-pairs x 32 col-groups; 16 rows/block; 625 blocks.
__global__ __launch_bounds__(256)
void gemm_bias_kernel(const float* __restrict__ h,
                      const float* __restrict__ W,
                      const float* __restrict__ b,
                      float* __restrict__ out) {
    __shared__ float Wl[kD * kD];   // 64 KB
    int t = threadIdx.x;
#pragma unroll
    for (int i = 0; i < 16; ++i) {
        int idx = t + i * 256;
        reinterpret_cast<float4*>(Wl)[idx] =
            reinterpret_cast<const float4*>(W)[idx];
    }
    __syncthreads();

    int rp   = t >> 5;                       // 0..7
    int j0   = (t & 31) * 4;
    int row0 = blockIdx.x * 16 + rp * 2;     // kNodes = 625*16 exactly
    const float* h0 = h + (size_t)row0 * kD;
    const float* h1 = h0 + kD;

    float4 acc0 = make_float4(0.f, 0.f, 0.f, 0.f);
    float4 acc1 = make_float4(0.f, 0.f, 0.f, 0.f);
#pragma unroll 4
    for (int k = 0; k < kD; k += 4) {
        float4 a0 = *reinterpret_cast<const float4*>(h0 + k);
        float4 a1 = *reinterpret_cast<const float4*>(h1 + k);
        const float* wk = Wl + (size_t)k * kD + j0;
        float4 w0 = *reinterpret_cast<const float4*>(wk + 0 * kD);
        float4 w1 = *reinterpret_cast<const float4*>(wk + 1 * kD);
        float4 w2 = *reinterpret_cast<const float4*>(wk + 2 * kD);
        float4 w3 = *reinterpret_cast<const float4*>(wk + 3 * kD);
        acc0.x += a0.x * w0.x + a0.y * w1.x + a0.z * w2.x + a0.w * w3.x;
        acc0.y += a0.x * w0.y + a0.y * w1.y + a0.z * w2.y + a0.w * w3.y;
        acc0.z += a0.x * w0.z + a0.y * w1.z + a0.z * w2.z + a0.w * w3.z;
        acc0.w += a0.x * w0.w + a0.y * w1.w + a0.z * w2.w + a0.w * w3.w;
        acc1.x += a1.x * w0.x + a1.y * w1.x + a1.z * w2.x + a1.w * w3.x;
        acc1.y += a1.x * w0.y + a1.y * w1.y + a1.z * w2.y + a1.w * w3.y;
        acc1.z += a1.x * w0.z + a1.y * w1.z + a1.z * w2.z + a1.w * w3.z;
        acc1.w += a1.x * w0.w + a1.y * w1.w + a1.z * w2.w + a1.w * w3.w;
    }
    const float4 bb = *reinterpret_cast<const float4*>(b + j0);
    acc0.x += bb.x; acc0.y += bb.y; acc0.z += bb.z; acc0.w += bb.w;
    acc1.x += bb.x; acc1.y += bb.y; acc1.z += bb.z; acc1.w += bb.w;
    *reinterpret_cast<float4*>(out + (size_t)row0 * kD + j0) = acc0;
    *reinterpret_cast<float4*>(out + (size_t)(row0 + 1) * kD + j0) = acc1;
}

extern "C" void kernel_launch(void* const* d_in, const int* in_sizes, int n_in,
                              void* d_out, int out_size, void* d_ws, size_t ws_size,
                              hipStream_t stream) {
    const float* feature = (const float*)d_in[0];
    const int*   src     = (const int*)d_in[1];
    const int*   dst     = (const int*)d_in[2];
    const float* W       = (const float*)d_in[3];
    const float* b       = (const float*)d_in[4];
    float*       out     = (float*)d_out;

    // Workspace layout
    //   h      : kNodes*kD floats        (5,120,000 B)
    //   head   : kNodes*kChains ints     (  160,000 B)
    //   packed : kEdges int2             (5,120,000 B)
    char* ws = (char*)d_ws;
    size_t off = 0;
    float* h      = (float*)(ws + off);  off += (size_t)kNodes * kD * sizeof(float);
    int*   head   = (int*)(ws + off);    off += (size_t)kNodes * kChains * sizeof(int);
    // align packed to 8B
    off = (off + 7) & ~(size_t)7;
    int2*  packed = (int2*)(ws + off);   off += (size_t)kEdges * sizeof(int2);
    const size_t needed = off;

    if (ws_size >= needed) {
        // head = -1 everywhere
        hipMemsetAsync(head, 0xFF, (size_t)kNodes * kChains * sizeof(int), stream);

        int threads = 256;
        int eblocks = (kEdges + threads - 1) / threads;
        build_ll_kernel<<<eblocks, threads, 0, stream>>>(src, dst, head, packed);

        int waves_per_block = threads / 64;
        int gblocks = (kNodes + waves_per_block - 1) / waves_per_block;
        gather_ll_kernel<<<gblocks, threads, 0, stream>>>(feature, head, packed, h);
    } else {
        // Path A fallback: atomic scatter
        hipMemsetAsync(h, 0, (size_t)kNodes * kD * sizeof(float), stream);
        long long total = (long long)kEdges * 32;
        int threads = 256;
        int blocks  = (int)((total + threads - 1) / threads);
        scatter_add_kernel<<<blocks, threads, 0, stream>>>(feature, src, dst, h);
    }

    {   // GEMM + bias: 16 rows per 256-thread block (10000 = 625*16)
        gemm_bias_kernel<<<kNodes / 16, 256, 0, stream>>>(h, W, b, out);
    }
}

// Round 5
// 133.103 us; speedup vs baseline: 8.2654x; 1.0682x over previous
//
#include <hip/hip_runtime.h>

constexpr int kNodes = 10000;
constexpr int kEdges = 640000;
constexpr int kD = 128;

typedef unsigned int  u32;
typedef unsigned short u16;

__device__ inline u16 f2bf(float x) {             // round-to-nearest-even
    u32 u = __float_as_uint(x);
    u32 r = u + 0x7FFF + ((u >> 16) & 1);
    return (u16)(r >> 16);
}

// ---------------------------------------------------------------------------
// Path A (fallback): direct atomic scatter-add + fp32 GEMM
// ---------------------------------------------------------------------------
__global__ void scatter_add_kernel(const float* __restrict__ feature,
                                   const int* __restrict__ src,
                                   const int* __restrict__ dst,
                                   float* __restrict__ h) {
    long long tid = (long long)blockIdx.x * blockDim.x + threadIdx.x;
    int e    = (int)(tid >> 5);
    int lane = (int)(tid & 31);
    if (e >= kEdges) return;
    int s = src[e];
    int d = dst[e];
    const float4 v = *reinterpret_cast<const float4*>(feature + (size_t)s * kD + lane * 4);
    float* hp = h + (size_t)d * kD + lane * 4;
    atomicAdd(hp + 0, v.x);
    atomicAdd(hp + 1, v.y);
    atomicAdd(hp + 2, v.z);
    atomicAdd(hp + 3, v.w);
}

__global__ __launch_bounds__(256)
void gemm_bias_kernel(const float* __restrict__ h,
                      const float* __restrict__ W,
                      const float* __restrict__ b,
                      float* __restrict__ out) {
    __shared__ float Wl[kD * kD];
    int t = threadIdx.x;
#pragma unroll
    for (int i = 0; i < 16; ++i) {
        int idx = t + i * 256;
        reinterpret_cast<float4*>(Wl)[idx] = reinterpret_cast<const float4*>(W)[idx];
    }
    __syncthreads();
    int row = blockIdx.x * 8 + (t >> 5);
    int j0  = (t & 31) * 4;
    if (row >= kNodes) return;
    const float* hrow = h + (size_t)row * kD;
    float4 acc = make_float4(0.f, 0.f, 0.f, 0.f);
#pragma unroll 4
    for (int k = 0; k < kD; k += 4) {
        float4 hv4 = *reinterpret_cast<const float4*>(hrow + k);
        const float* wk = Wl + (size_t)k * kD + j0;
        float4 w0 = *reinterpret_cast<const float4*>(wk + 0 * kD);
        float4 w1 = *reinterpret_cast<const float4*>(wk + 1 * kD);
        float4 w2 = *reinterpret_cast<const float4*>(wk + 2 * kD);
        float4 w3 = *reinterpret_cast<const float4*>(wk + 3 * kD);
        acc.x += hv4.x * w0.x + hv4.y * w1.x + hv4.z * w2.x + hv4.w * w3.x;
        acc.y += hv4.x * w0.y + hv4.y * w1.y + hv4.z * w2.y + hv4.w * w3.y;
        acc.z += hv4.x * w0.z + hv4.y * w1.z + hv4.z * w2.z + hv4.w * w3.z;
        acc.w += hv4.x * w0.w + hv4.y * w1.w + hv4.z * w2.w + hv4.w * w3.w;
    }
    const float4 bb = *reinterpret_cast<const float4*>(b + j0);
    acc.x += bb.x; acc.y += bb.y; acc.z += bb.z; acc.w += bb.w;
    *reinterpret_cast<float4*>(out + (size_t)row * kD + j0) = acc;
}

// ---------------------------------------------------------------------------
// Path B: FW = feature @ W (bf16), CSR build, L2-resident bf16 gather
// ---------------------------------------------------------------------------

// FW[row][j] = sum_k feature[row][k] * W[k][j], stored bf16.
// 256 threads = 8 row-pairs x 32 col-groups; 16 rows/block; 625 blocks.
__global__ __launch_bounds__(256)
void gemm_fw_kernel(const float* __restrict__ feature,
                    const float* __restrict__ W,
                    u16* __restrict__ FW) {
    __shared__ float Wl[kD * kD];
    int t = threadIdx.x;
#pragma unroll
    for (int i = 0; i < 16; ++i) {
        int idx = t + i * 256;
        reinterpret_cast<float4*>(Wl)[idx] = reinterpret_cast<const float4*>(W)[idx];
    }
    __syncthreads();

    int rp   = t >> 5;
    int j0   = (t & 31) * 4;
    int row0 = blockIdx.x * 16 + rp * 2;      // 10000 = 625*16 exactly
    const float* h0 = feature + (size_t)row0 * kD;
    const float* h1 = h0 + kD;

    float4 acc0 = make_float4(0.f, 0.f, 0.f, 0.f);
    float4 acc1 = make_float4(0.f, 0.f, 0.f, 0.f);
#pragma unroll 4
    for (int k = 0; k < kD; k += 4) {
        float4 a0 = *reinterpret_cast<const float4*>(h0 + k);
        float4 a1 = *reinterpret_cast<const float4*>(h1 + k);
        const float* wk = Wl + (size_t)k * kD + j0;
        float4 w0 = *reinterpret_cast<const float4*>(wk + 0 * kD);
        float4 w1 = *reinterpret_cast<const float4*>(wk + 1 * kD);
        float4 w2 = *reinterpret_cast<const float4*>(wk + 2 * kD);
        float4 w3 = *reinterpret_cast<const float4*>(wk + 3 * kD);
        acc0.x += a0.x * w0.x + a0.y * w1.x + a0.z * w2.x + a0.w * w3.x;
        acc0.y += a0.x * w0.y + a0.y * w1.y + a0.z * w2.y + a0.w * w3.y;
        acc0.z += a0.x * w0.z + a0.y * w1.z + a0.z * w2.z + a0.w * w3.z;
        acc0.w += a0.x * w0.w + a0.y * w1.w + a0.z * w2.w + a0.w * w3.w;
        acc1.x += a1.x * w0.x + a1.y * w1.x + a1.z * w2.x + a1.w * w3.x;
        acc1.y += a1.x * w0.y + a1.y * w1.y + a1.z * w2.y + a1.w * w3.y;
        acc1.z += a1.x * w0.z + a1.y * w1.z + a1.z * w2.z + a1.w * w3.z;
        acc1.w += a1.x * w0.w + a1.y * w1.w + a1.z * w2.w + a1.w * w3.w;
    }
    u32 lo0 = (u32)f2bf(acc0.x) | ((u32)f2bf(acc0.y) << 16);
    u32 hi0 = (u32)f2bf(acc0.z) | ((u32)f2bf(acc0.w) << 16);
    u32 lo1 = (u32)f2bf(acc1.x) | ((u32)f2bf(acc1.y) << 16);
    u32 hi1 = (u32)f2bf(acc1.z) | ((u32)f2bf(acc1.w) << 16);
    *reinterpret_cast<uint2*>(FW + (size_t)row0 * kD + j0)       = make_uint2(lo0, hi0);
    *reinterpret_cast<uint2*>(FW + (size_t)(row0 + 1) * kD + j0) = make_uint2(lo1, hi1);
}

__global__ void histogram_kernel(const int* __restrict__ dst,
                                 int* __restrict__ counts) {
    int e = blockIdx.x * blockDim.x + threadIdx.x;
    if (e >= kEdges) return;
    atomicAdd(&counts[dst[e]], 1);
}

constexpr int kScanThreads = 1024;
constexpr int kPerThread   = 10;   // 1024*10 >= kNodes

__global__ __launch_bounds__(kScanThreads)
void scan_kernel(const int* __restrict__ counts,
                 int* __restrict__ offsets,
                 int* __restrict__ cursor) {
    __shared__ int lds[kScanThreads];
    int t = threadIdx.x;
    int base = t * kPerThread;

    int v[kPerThread];
    int sum = 0;
#pragma unroll
    for (int i = 0; i < kPerThread; ++i) {
        int idx = base + i;
        v[i] = (idx < kNodes) ? counts[idx] : 0;
        sum += v[i];
    }
    lds[t] = sum;
    __syncthreads();
#pragma unroll
    for (int off = 1; off < kScanThreads; off <<= 1) {
        int add = (t >= off) ? lds[t - off] : 0;
        __syncthreads();
        lds[t] += add;
        __syncthreads();
    }
    int excl = lds[t] - sum;
    int run = excl;
#pragma unroll
    for (int i = 0; i < kPerThread; ++i) {
        int idx = base + i;
        if (idx < kNodes) {
            offsets[idx] = run;
            cursor[idx]  = run;
        }
        run += v[i];
    }
    if (t == 0) offsets[kNodes] = lds[kScanThreads - 1];
}

__global__ void fill_kernel(const int* __restrict__ src,
                            const int* __restrict__ dst,
                            int* __restrict__ cursor,
                            int* __restrict__ csr_src) {
    int e = blockIdx.x * blockDim.x + threadIdx.x;
    if (e >= kEdges) return;
    int d   = dst[e];
    int pos = atomicAdd(&cursor[d], 1);
    csr_src[pos] = src[e];
}

// One 64-lane wave per node; lane owns 2 dims (one u32 = 2 bf16 per row read).
// out[node] = sum_{e in CSR[node]} FW[src[e]] + b
__global__ void gather_csr_kernel(const u16* __restrict__ FW,
                                  const int* __restrict__ offsets,
                                  const int* __restrict__ csr_src,
                                  const float* __restrict__ b,
                                  float* __restrict__ out) {
    int node = blockIdx.x * (blockDim.x >> 6) + (threadIdx.x >> 6);
    int lane = threadIdx.x & 63;
    if (node >= kNodes) return;
    int beg = offsets[node];
    int end = offsets[node + 1];

    float ax = 0.f, ay = 0.f;
    int i = beg;
    for (; i + 8 <= end; i += 8) {
        u32 v[8];
#pragma unroll
        for (int u = 0; u < 8; ++u) {
            int s = csr_src[i + u];
            v[u] = *reinterpret_cast<const u32*>(FW + (size_t)s * kD + lane * 2);
        }
#pragma unroll
        for (int u = 0; u < 8; ++u) {
            ax += __uint_as_float(v[u] << 16);
            ay += __uint_as_float(v[u] & 0xFFFF0000u);
        }
    }
    for (; i < end; ++i) {
        int s = csr_src[i];
        u32 v = *reinterpret_cast<const u32*>(FW + (size_t)s * kD + lane * 2);
        ax += __uint_as_float(v << 16);
        ay += __uint_as_float(v & 0xFFFF0000u);
    }

    const float2 bb = *reinterpret_cast<const float2*>(b + lane * 2);
    float2 r = make_float2(ax + bb.x, ay + bb.y);
    *reinterpret_cast<float2*>(out + (size_t)node * kD + lane * 2) = r;
}

extern "C" void kernel_launch(void* const* d_in, const int* in_sizes, int n_in,
                              void* d_out, int out_size, void* d_ws, size_t ws_size,
                              hipStream_t stream) {
    const float* feature = (const float*)d_in[0];
    const int*   src     = (const int*)d_in[1];
    const int*   dst     = (const int*)d_in[2];
    const float* W       = (const float*)d_in[3];
    const float* b       = (const float*)d_in[4];
    float*       out     = (float*)d_out;

    // Workspace layout (Path B)
    //   FW      : kNodes*kD u16      (2,560,000 B)
    //   counts  : kNodes int         (   40,000 B)
    //   offsets : kNodes+1 int       (   40,004 B)
    //   cursor  : kNodes int         (   40,000 B)
    //   csr_src : kEdges int         (2,560,000 B)
    char* ws = (char*)d_ws;
    size_t off = 0;
    u16* FW      = (u16*)(ws + off);  off += (size_t)kNodes * kD * sizeof(u16);
    int* counts  = (int*)(ws + off);  off += (size_t)kNodes * sizeof(int);
    int* offsets = (int*)(ws + off);  off += (size_t)(kNodes + 1) * sizeof(int);
    int* cursor  = (int*)(ws + off);  off += (size_t)kNodes * sizeof(int);
    int* csr_src = (int*)(ws + off);  off += (size_t)kEdges * sizeof(int);
    const size_t neededB = off;
    const size_t neededA = (size_t)kNodes * kD * sizeof(float);

    int threads = 256;
    int eblocks = (kEdges + threads - 1) / threads;

    if (ws_size >= neededB) {
        hipMemsetAsync(counts, 0, (size_t)kNodes * sizeof(int), stream);

        histogram_kernel<<<eblocks, threads, 0, stream>>>(dst, counts);
        scan_kernel<<<1, kScanThreads, 0, stream>>>(counts, offsets, cursor);
        gemm_fw_kernel<<<kNodes / 16, 256, 0, stream>>>(feature, W, FW);  // independent; placed here
        fill_kernel<<<eblocks, threads, 0, stream>>>(src, dst, cursor, csr_src);

        int gblocks = (kNodes + 3) / 4;   // 4 waves/block
        gather_csr_kernel<<<gblocks, 256, 0, stream>>>(FW, offsets, csr_src, b, out);
    } else if (ws_size >= neededA) {
        float* h = (float*)d_ws;
        hipMemsetAsync(h, 0, neededA, stream);
        long long total = (long long)kEdges * 32;
        int blocks = (int)((total + threads - 1) / threads);
        scatter_add_kernel<<<blocks, threads, 0, stream>>>(feature, src, dst, h);
        gemm_bias_kernel<<<(kNodes + 7) / 8, 256, 0, stream>>>(h, W, b, out);
    }
}